// Round 17
// baseline (173.164 us; speedup 1.0000x reference)
//
#include <hip/hip_runtime.h>
#include <math.h>

#define NPOL   1000
#define NTICK  98000
#define NCOMM  1000
#define NN     100000
#define NE     1000000

#define BKTSHIFT 9       // 512 nodes per bucket
#define NBKT     196     // ceil(NN/512)
#define BKTCAP   6144    // mean 5120 -> large headroom
#define KA_EPB   4096    // edges per bucket block
#define KA_BLOCKS 245    // ceil(NE/4096)
#define FEATBLKS  391    // ceil(NN*4/1024)

__device__ __forceinline__ unsigned short f2bf(float v) {
    unsigned u = __float_as_uint(v);
    u += 0x7FFFu + ((u >> 16) & 1u);          // round-to-nearest-even
    return (unsigned short)(u >> 16);
}
__device__ __forceinline__ float bf2f(unsigned short s) {
    return __uint_as_float(((unsigned)s) << 16);
}

// ---------------------------------------------------------------------------
__global__ void k_zero(int* __restrict__ bucket_cnt) {
    for (int i = threadIdx.x; i < NBKT * 16; i += 1024) bucket_cnt[i] = 0;
}

// ---------------------------------------------------------------------------
// K_FEATBUCKET: blocks [0,KA_BLOCKS) = edge bucketing (memory/atomic-bound);
// blocks [KA_BLOCKS,..) = node features->LN->h1->as1/ad1 (LDS/VALU-bound).
__global__ void __launch_bounds__(1024) k_featbucket(
    const int* __restrict__ ei, const float* __restrict__ edge_attr,
    const float* __restrict__ c1_eW, const float* __restrict__ c1_ae,
    const float* __restrict__ c2_eW, const float* __restrict__ c2_ae,
    int* __restrict__ bucket_cnt, float4* __restrict__ bucketbuf,
    const float* __restrict__ pol_feat, const int* __restrict__ state_ids,
    const int* __restrict__ sector_ids, const int* __restrict__ industry_ids,
    const float* __restrict__ comp_scalar,
    const float* __restrict__ pol_W, const float* __restrict__ pol_b,
    const float* __restrict__ state_E, const float* __restrict__ sector_E,
    const float* __restrict__ industry_E, const float* __restrict__ comp_W,
    const float* __restrict__ comp_b, const float* __restrict__ comm_E,
    const float* __restrict__ ln_g, const float* __restrict__ ln_b,
    const float* __restrict__ c1_W, const float* __restrict__ c1_as,
    const float* __restrict__ c1_ad,
    unsigned short* __restrict__ h1b, float* __restrict__ as1,
    float* __restrict__ ad1) {
    int t = threadIdx.x;
    if (blockIdx.x < KA_BLOCKS) {
        __shared__ float we1s[20];
        __shared__ float we2s[5];
        __shared__ int hcnt[NBKT];
        __shared__ int hbase[NBKT];
        if (t < 20) {
            int d = t >> 2, h = t & 3;
            float s = 0.f;
            for (int f = 0; f < 16; ++f) s += c1_eW[d * 64 + h * 16 + f] * c1_ae[h * 16 + f];
            we1s[t] = s;
        } else if (t >= 32 && t < 37) {
            int d = t - 32;
            float s = 0.f;
            for (int f = 0; f < 32; ++f) s += c2_eW[d * 32 + f] * c2_ae[f];
            we2s[d] = s;
        }
        if (t < NBKT) hcnt[t] = 0;
        __syncthreads();
        int e0 = blockIdx.x * KA_EPB + t;
        int bk[4], rk[4];
        float4 rec[4];
        #pragma unroll
        for (int k = 0; k < 4; ++k) {
            int e = e0 + k * 1024;
            bk[k] = -1;
            if (e < NE) {
                int s = ei[e];
                int d = ei[NE + e];
                int bkt = d >> BKTSHIFT;
                int dl = d & ((1 << BKTSHIFT) - 1);
                float a[5];
                #pragma unroll
                for (int kk = 0; kk < 5; ++kk) a[kk] = edge_attr[e * 5 + kk];
                float v0 = 0.f, v1 = 0.f, v2 = 0.f, v3 = 0.f, v4 = 0.f;
                #pragma unroll
                for (int kk = 0; kk < 5; ++kk) {
                    v0 += a[kk] * we1s[kk * 4 + 0];
                    v1 += a[kk] * we1s[kk * 4 + 1];
                    v2 += a[kk] * we1s[kk * 4 + 2];
                    v3 += a[kk] * we1s[kk * 4 + 3];
                    v4 += a[kk] * we2s[kk];
                }
                unsigned u01 = (unsigned)f2bf(v0) | ((unsigned)f2bf(v1) << 16);
                unsigned u23 = (unsigned)f2bf(v2) | ((unsigned)f2bf(v3) << 16);
                unsigned pk = (unsigned)s | ((unsigned)dl << 17);
                rec[k] = make_float4(__uint_as_float(pk), __uint_as_float(u01),
                                     __uint_as_float(u23), v4);
                bk[k] = bkt;
                rk[k] = atomicAdd(&hcnt[bkt], 1);
            }
        }
        __syncthreads();
        if (t < NBKT && hcnt[t] > 0) hbase[t] = atomicAdd(&bucket_cnt[t * 16], hcnt[t]);
        __syncthreads();
        #pragma unroll
        for (int k = 0; k < 4; ++k) {
            if (bk[k] >= 0) {
                int pos = hbase[bk[k]] + rk[k];
                if (pos < BKTCAP)
                    bucketbuf[(size_t)bk[k] * BKTCAP + pos] = rec[k];
            }
        }
        return;
    }
    // ---------------- feat part ----------------
    __shared__ float sW1[2048];
    __shared__ float sCompW[544];
    __shared__ float sPolW[224];
    __shared__ float sAs[64], sAd[64];
    __shared__ float sLg[32], sLb[32], sPb[32], sCb[32];
    for (int i = t; i < 2048; i += 1024) sW1[i] = c1_W[i];
    if (t < 544) sCompW[t] = comp_W[t];
    if (t >= 544 && t < 768) sPolW[t - 544] = pol_W[t - 544];
    if (t >= 768 && t < 832) { sAs[t - 768] = c1_as[t - 768]; sAd[t - 768] = c1_ad[t - 768]; }
    if (t >= 832 && t < 864) {
        int i = t - 832;
        sLg[i] = ln_g[i]; sLb[i] = ln_b[i]; sPb[i] = pol_b[i]; sCb[i] = comp_b[i];
    }
    __syncthreads();
    int tid = (blockIdx.x - KA_BLOCKS) * 1024 + t;
    if (tid >= 4 * NN) return;
    int n = tid >> 2, q = tid & 3, jb = q * 8;
    float x[8];
    if (n < NPOL) {
        float f[7];
        #pragma unroll
        for (int i = 0; i < 7; ++i) f[i] = pol_feat[n * 7 + i];
        int sid = state_ids[n];
        #pragma unroll
        for (int jj = 0; jj < 8; ++jj) {
            int j = jb + jj;
            float v = sPb[j];
            #pragma unroll
            for (int i = 0; i < 7; ++i) v += f[i] * sPolW[i * 32 + j];
            v = v > 0.f ? v : 0.f;
            x[jj] = v + state_E[sid * 32 + j];
        }
    } else if (n < NPOL + NTICK) {
        int tt = n - NPOL;
        float f[17];
        int sec = sector_ids[tt], ind = industry_ids[tt];
        #pragma unroll
        for (int i = 0; i < 8; ++i) { f[i] = sector_E[sec * 8 + i]; f[8 + i] = industry_E[ind * 8 + i]; }
        f[16] = comp_scalar[tt];
        #pragma unroll
        for (int jj = 0; jj < 8; ++jj) {
            int j = jb + jj;
            float v = sCb[j];
            #pragma unroll
            for (int i = 0; i < 17; ++i) v += f[i] * sCompW[i * 32 + j];
            x[jj] = v > 0.f ? v : 0.f;
        }
    } else {
        int c = n - (NPOL + NTICK);
        float4 a = *(const float4*)&comm_E[c * 32 + jb];
        float4 b = *(const float4*)&comm_E[c * 32 + jb + 4];
        x[0] = a.x; x[1] = a.y; x[2] = a.z; x[3] = a.w;
        x[4] = b.x; x[5] = b.y; x[6] = b.z; x[7] = b.w;
    }
    float s1 = 0.f;
    #pragma unroll
    for (int jj = 0; jj < 8; ++jj) s1 += x[jj];
    s1 += __shfl_xor(s1, 1); s1 += __shfl_xor(s1, 2);
    float mu = s1 * (1.f / 32.f);
    float s2 = 0.f;
    #pragma unroll
    for (int jj = 0; jj < 8; ++jj) { float dd = x[jj] - mu; s2 += dd * dd; }
    s2 += __shfl_xor(s2, 1); s2 += __shfl_xor(s2, 2);
    float inv = rsqrtf(s2 * (1.f / 32.f) + 1e-5f);
    #pragma unroll
    for (int jj = 0; jj < 8; ++jj) x[jj] = (x[jj] - mu) * inv * sLg[jb + jj] + sLb[jb + jj];
    float4 acc0 = {0,0,0,0}, acc1 = {0,0,0,0}, acc2 = {0,0,0,0}, acc3 = {0,0,0,0};
    int qb = (t & 63) & ~3;
    int jc = q * 16;
    #pragma unroll
    for (int p = 0; p < 4; ++p) {
        #pragma unroll
        for (int jj = 0; jj < 8; ++jj) {
            float xs = __shfl(x[jj], qb + p, 64);
            const float4* wr = (const float4*)&sW1[(p * 8 + jj) * 64 + jc];
            float4 w0 = wr[0], w1 = wr[1], w2 = wr[2], w3 = wr[3];
            acc0.x = fmaf(xs, w0.x, acc0.x); acc0.y = fmaf(xs, w0.y, acc0.y);
            acc0.z = fmaf(xs, w0.z, acc0.z); acc0.w = fmaf(xs, w0.w, acc0.w);
            acc1.x = fmaf(xs, w1.x, acc1.x); acc1.y = fmaf(xs, w1.y, acc1.y);
            acc1.z = fmaf(xs, w1.z, acc1.z); acc1.w = fmaf(xs, w1.w, acc1.w);
            acc2.x = fmaf(xs, w2.x, acc2.x); acc2.y = fmaf(xs, w2.y, acc2.y);
            acc2.z = fmaf(xs, w2.z, acc2.z); acc2.w = fmaf(xs, w2.w, acc2.w);
            acc3.x = fmaf(xs, w3.x, acc3.x); acc3.y = fmaf(xs, w3.y, acc3.y);
            acc3.z = fmaf(xs, w3.z, acc3.z); acc3.w = fmaf(xs, w3.w, acc3.w);
        }
    }
    const float4* asv = (const float4*)sAs;
    const float4* adv = (const float4*)sAd;
    float4 a0 = asv[q * 4], a1 = asv[q * 4 + 1], a2 = asv[q * 4 + 2], a3 = asv[q * 4 + 3];
    float4 b0 = adv[q * 4], b1v = adv[q * 4 + 1], b2v = adv[q * 4 + 2], b3 = adv[q * 4 + 3];
    float av = acc0.x * a0.x + acc0.y * a0.y + acc0.z * a0.z + acc0.w * a0.w
             + acc1.x * a1.x + acc1.y * a1.y + acc1.z * a1.z + acc1.w * a1.w
             + acc2.x * a2.x + acc2.y * a2.y + acc2.z * a2.z + acc2.w * a2.w
             + acc3.x * a3.x + acc3.y * a3.y + acc3.z * a3.z + acc3.w * a3.w;
    float dv = acc0.x * b0.x + acc0.y * b0.y + acc0.z * b0.z + acc0.w * b0.w
             + acc1.x * b1v.x + acc1.y * b1v.y + acc1.z * b1v.z + acc1.w * b1v.w
             + acc2.x * b2v.x + acc2.y * b2v.y + acc2.z * b2v.z + acc2.w * b2v.w
             + acc3.x * b3.x + acc3.y * b3.y + acc3.z * b3.z + acc3.w * b3.w;
    as1[tid] = av;
    ad1[tid] = dv;
    uint4 w1o, w2o;
    w1o.x = (unsigned)f2bf(acc0.x) | ((unsigned)f2bf(acc0.y) << 16);
    w1o.y = (unsigned)f2bf(acc0.z) | ((unsigned)f2bf(acc0.w) << 16);
    w1o.z = (unsigned)f2bf(acc1.x) | ((unsigned)f2bf(acc1.y) << 16);
    w1o.w = (unsigned)f2bf(acc1.z) | ((unsigned)f2bf(acc1.w) << 16);
    w2o.x = (unsigned)f2bf(acc2.x) | ((unsigned)f2bf(acc2.y) << 16);
    w2o.y = (unsigned)f2bf(acc2.z) | ((unsigned)f2bf(acc2.w) << 16);
    w2o.z = (unsigned)f2bf(acc3.x) | ((unsigned)f2bf(acc3.y) << 16);
    w2o.w = (unsigned)f2bf(acc3.z) | ((unsigned)f2bf(acc3.w) << 16);
    unsigned short* hp = h1b + (unsigned)n * 64u + (unsigned)jc;
    *(uint4*)hp = w1o;
    *(uint4*)(hp + 8) = w2o;
}

// ---------------------------------------------------------------------------
// K_SORTFILL: one block per bucket (unchanged).
__global__ void __launch_bounds__(1024) k_sortfill(
    const int* __restrict__ bucket_cnt, const float4* __restrict__ bucketbuf,
    float4* __restrict__ rec2, int* __restrict__ deg, int* __restrict__ erow) {
    __shared__ int pref[256];
    __shared__ int hist[512];
    __shared__ int hoff[512];
    int t = threadIdx.x;
    int b = blockIdx.x;
    if (t < 256) pref[t] = (t < NBKT) ? bucket_cnt[t * 16] : 0;
    if (t < 512) hist[t] = 0;
    __syncthreads();
    for (int off = 1; off < 256; off <<= 1) {
        int v = 0;
        if (t < 256 && t >= off) v = pref[t - off];
        __syncthreads();
        if (t < 256) pref[t] += v;
        __syncthreads();
    }
    int count = bucket_cnt[b * 16];
    if (count > BKTCAP) count = BKTCAP;
    int region = (b == 0) ? 0 : pref[b - 1];
    float4 rv[6];
    int dlv[6], rrv[6];
    #pragma unroll
    for (int k = 0; k < 6; ++k) {
        int i = k * 1024 + t;
        dlv[k] = -1;
        if (i < count) {
            float4 p = bucketbuf[(size_t)b * BKTCAP + i];
            int dl = (int)(__float_as_uint(p.x) >> 17);
            p.x = __uint_as_float(__float_as_uint(p.x) & 0x1FFFFu);
            rv[k] = p;
            dlv[k] = dl;
            rrv[k] = atomicAdd(&hist[dl], 1);
        }
    }
    __syncthreads();
    if (t < 512) hoff[t] = hist[t];
    __syncthreads();
    for (int off = 1; off < 512; off <<= 1) {
        int v = 0;
        if (t < 512 && t >= off) v = hoff[t - off];
        __syncthreads();
        if (t < 512) hoff[t] += v;
        __syncthreads();
    }
    #pragma unroll
    for (int k = 0; k < 6; ++k) {
        if (dlv[k] >= 0) {
            int pos = region + hoff[dlv[k]] - hist[dlv[k]] + rrv[k];
            rec2[pos] = rv[k];
        }
    }
    int n = (b << BKTSHIFT) + t;
    if (t < 512 && n < NN) {
        deg[n] = hist[t];
        erow[n] = region + hoff[t] - hist[t];
    }
}

// ---------------------------------------------------------------------------
// K_AGG1: GAT layer 1 aggregation only (2 nodes/wave), lean epilogue ending at
// the ELU + coalesced bf16 x1 write. The mid GEMV is a separate kernel again —
// fused (R14/R16) it doubled this kernel's per-wave instruction count and ran
// at poor IPC interleaved with gather stalls (60us vs 41+10 split).
__global__ void __launch_bounds__(256) k_agg1(
    const int* __restrict__ erow, const int* __restrict__ deg,
    const float4* __restrict__ rec2,
    const float* __restrict__ as1, const float* __restrict__ ad1,
    const unsigned short* __restrict__ h1b, const float* __restrict__ c1_b,
    unsigned short* __restrict__ x1b, float* __restrict__ selfae2) {
    __shared__ float pT[4][2][32][4];
    __shared__ int   srcT[4][2][32];
    int wid = threadIdx.x >> 6;
    int lane = threadIdx.x & 63;
    int half = lane >> 5;
    int j = lane & 31;
    int h = j >> 3;
    int n = blockIdx.x * 8 + wid * 2 + half;
    int base = erow[n];
    int dg   = deg[n];
    const float4* as1v4 = (const float4*)as1;
    const float4* ad1v4 = (const float4*)ad1;
    float4 adv = ad1v4[n];
    float4 asv = as1v4[n];
    unsigned uself = *(const unsigned*)(h1b + (unsigned)n * 64u + 2u * (unsigned)j);

    float ssum = 0.f, acc0 = 0.f, acc1 = 0.f;
    float aes0 = 0.f, aes1 = 0.f, aes2 = 0.f, aes3 = 0.f, ae2sum = 0.f;

    for (int i0 = 0; i0 < dg; i0 += 32) {
        int clen = dg - i0; if (clen > 32) clen = 32;
        int idx = i0 + j;
        if (idx < dg) {
            float4 r = rec2[base + idx];
            int s = __float_as_int(r.x);
            unsigned u01 = __float_as_uint(r.y), u23 = __float_as_uint(r.z);
            float ae0  = bf2f((unsigned short)u01);
            float ae1v = bf2f((unsigned short)(u01 >> 16));
            float ae2v = bf2f((unsigned short)u23);
            float ae3v = bf2f((unsigned short)(u23 >> 16));
            float4 av = as1v4[s];
            float l0 = av.x + adv.x + ae0;  l0 = l0 > 0.f ? l0 : 0.2f * l0;
            float l1 = av.y + adv.y + ae1v; l1 = l1 > 0.f ? l1 : 0.2f * l1;
            float l2 = av.z + adv.z + ae2v; l2 = l2 > 0.f ? l2 : 0.2f * l2;
            float l3 = av.w + adv.w + ae3v; l3 = l3 > 0.f ? l3 : 0.2f * l3;
            float4 q = make_float4(__expf(l0), __expf(l1), __expf(l2), __expf(l3));
            *(float4*)&pT[wid][half][j][0] = q;
            srcT[wid][half][j] = s;
            aes0 += ae0; aes1 += ae1v; aes2 += ae2v; aes3 += ae3v;
            ae2sum += r.w;
        }
        int i = 0;
        for (; i + 4 <= clen; i += 4) {
            int s0 = srcT[wid][half][i],     s1 = srcT[wid][half][i + 1];
            int s2 = srcT[wid][half][i + 2], s3 = srcT[wid][half][i + 3];
            float q0 = pT[wid][half][i][h],     q1 = pT[wid][half][i + 1][h];
            float q2 = pT[wid][half][i + 2][h], q3 = pT[wid][half][i + 3][h];
            unsigned g0 = *(const unsigned*)(h1b + (unsigned)s0 * 64u + 2u * (unsigned)j);
            unsigned g1 = *(const unsigned*)(h1b + (unsigned)s1 * 64u + 2u * (unsigned)j);
            unsigned g2 = *(const unsigned*)(h1b + (unsigned)s2 * 64u + 2u * (unsigned)j);
            unsigned g3 = *(const unsigned*)(h1b + (unsigned)s3 * 64u + 2u * (unsigned)j);
            ssum += (q0 + q1) + (q2 + q3);
            acc0 = fmaf(q0, bf2f((unsigned short)g0),
                   fmaf(q1, bf2f((unsigned short)g1),
                   fmaf(q2, bf2f((unsigned short)g2),
                   fmaf(q3, bf2f((unsigned short)g3), acc0))));
            acc1 = fmaf(q0, bf2f((unsigned short)(g0 >> 16)),
                   fmaf(q1, bf2f((unsigned short)(g1 >> 16)),
                   fmaf(q2, bf2f((unsigned short)(g2 >> 16)),
                   fmaf(q3, bf2f((unsigned short)(g3 >> 16)), acc1))));
        }
        for (; i < clen; ++i) {
            int s0 = srcT[wid][half][i];
            float q0 = pT[wid][half][i][h];
            unsigned g0 = *(const unsigned*)(h1b + (unsigned)s0 * 64u + 2u * (unsigned)j);
            ssum += q0;
            acc0 = fmaf(q0, bf2f((unsigned short)g0), acc0);
            acc1 = fmaf(q0, bf2f((unsigned short)(g0 >> 16)), acc1);
        }
    }
    #pragma unroll
    for (int m = 1; m < 32; m <<= 1) {
        aes0 += __shfl_xor(aes0, m);
        aes1 += __shfl_xor(aes1, m);
        aes2 += __shfl_xor(aes2, m);
        aes3 += __shfl_xor(aes3, m);
        ae2sum += __shfl_xor(ae2sum, m);
    }
    float invd = 1.f / fmaxf((float)dg, 1.f);
    float aesh = (h == 0) ? aes0 : (h == 1) ? aes1 : (h == 2) ? aes2 : aes3;
    float adh  = (h == 0) ? adv.x : (h == 1) ? adv.y : (h == 2) ? adv.z : adv.w;
    float ash  = (h == 0) ? asv.x : (h == 1) ? asv.y : (h == 2) ? asv.z : asv.w;
    float ls = ash + adh + aesh * invd;
    ls = ls > 0.f ? ls : 0.2f * ls;
    float ps = __expf(ls);
    ssum += ps;
    acc0 = fmaf(ps, bf2f((unsigned short)uself), acc0);
    acc1 = fmaf(ps, bf2f((unsigned short)(uself >> 16)), acc1);
    if (lane == 0) selfae2[n] = ae2sum * invd;
    if (lane == 32) selfae2[n] = ae2sum * invd;
    float inv_s = 1.f / ssum;
    float x0 = acc0 * inv_s + c1_b[2 * j];
    float x1 = acc1 * inv_s + c1_b[2 * j + 1];
    x0 = (x0 > 0.f) ? x0 : (__expf(x0) - 1.f);   // ELU
    x1 = (x1 > 0.f) ? x1 : (__expf(x1) - 1.f);
    unsigned w = (unsigned)f2bf(x0) | ((unsigned)f2bf(x1) << 16);
    *(unsigned*)(x1b + (unsigned)n * 64u + 2u * (unsigned)j) = w;
}

// ---------------------------------------------------------------------------
// K_MID: wave-cooperative GEMV h2 = x1 @ c2_W (64->32) + as2/ad2 scalars.
// Standalone (R12 form): runs at high occupancy / good IPC in ~10us.
__global__ void __launch_bounds__(256) k_mid(
    const unsigned short* __restrict__ x1b, const float* __restrict__ c2_W,
    const float* __restrict__ c2_as, const float* __restrict__ c2_ad,
    unsigned short* __restrict__ h2b, float* __restrict__ as2,
    float* __restrict__ ad2) {
    int wave = (blockIdx.x * 256 + threadIdx.x) >> 6;   // 50000 waves
    int lane = threadIdx.x & 63;
    int half = lane >> 5, j = lane & 31;
    int n = wave * 2 + half;
    unsigned u = *(const unsigned*)(x1b + (unsigned)n * 64u + j * 2u);
    float acc = 0.f;
    #pragma unroll
    for (int t = 0; t < 32; ++t) {
        unsigned xu = (unsigned)__shfl((int)u, half * 32 + t, 64);
        float x0 = bf2f((unsigned short)xu);
        float x1 = bf2f((unsigned short)(xu >> 16));
        acc = fmaf(x0, c2_W[(2 * t) * 32 + j], acc);
        acc = fmaf(x1, c2_W[(2 * t + 1) * 32 + j], acc);
    }
    float a = acc * c2_as[j], b = acc * c2_ad[j];
    #pragma unroll
    for (int m = 16; m > 0; m >>= 1) {
        a += __shfl_xor(a, m, 64);
        b += __shfl_xor(b, m, 64);
    }
    if (j == 0) { as2[n] = a; ad2[n] = b; }
    h2b[(unsigned)n * 32u + j] = f2bf(acc);
}

// ---------------------------------------------------------------------------
// K7: GAT layer 2, one 32-lane group per dst; self via selfae2 (unchanged).
__global__ void __launch_bounds__(256) k_agg2(
    const int* __restrict__ erow, const int* __restrict__ deg,
    const float4* __restrict__ rec2, const float* __restrict__ as2,
    const float* __restrict__ ad2, const float* __restrict__ selfae2,
    const unsigned short* __restrict__ h2b, const float* __restrict__ c2_b,
    float* __restrict__ out) {
    __shared__ float2 spT[8][32];
    int t = threadIdx.x;
    int half = t >> 5;
    int l32 = t & 31;
    int n = blockIdx.x * 8 + half;
    int base = erow[n];
    int dg = deg[n];
    float ad2n = ad2[n];
    float ssum = 0.f, acc = 0.f;
    for (int i0 = 0; i0 < dg; i0 += 32) {
        int clen = dg - i0; if (clen > 32) clen = 32;
        int idx = i0 + l32;
        float p = 0.f; int s = 0;
        if (idx < dg) {
            float4 r = rec2[base + idx];
            s = __float_as_int(r.x);
            float l = as2[s] + ad2n + r.w;
            l = l > 0.f ? l : 0.2f * l;
            p = __expf(l);
        }
        ssum += p;
        spT[half][l32] = make_float2(__int_as_float(s), p);
        int i = 0;
        for (; i + 4 <= clen; i += 4) {
            float2 e0 = spT[half][i],     e1 = spT[half][i + 1];
            float2 e2 = spT[half][i + 2], e3 = spT[half][i + 3];
            int s0 = __float_as_int(e0.x), s1 = __float_as_int(e1.x);
            int s2 = __float_as_int(e2.x), s3 = __float_as_int(e3.x);
            float g0 = bf2f(h2b[(unsigned)s0 * 32u + l32]);
            float g1 = bf2f(h2b[(unsigned)s1 * 32u + l32]);
            float g2 = bf2f(h2b[(unsigned)s2 * 32u + l32]);
            float g3 = bf2f(h2b[(unsigned)s3 * 32u + l32]);
            acc = fmaf(e0.y, g0, fmaf(e1.y, g1, fmaf(e2.y, g2, fmaf(e3.y, g3, acc))));
        }
        for (; i < clen; ++i) {
            float2 e0 = spT[half][i];
            int s0 = __float_as_int(e0.x);
            acc = fmaf(e0.y, bf2f(h2b[(unsigned)s0 * 32u + l32]), acc);
        }
    }
    #pragma unroll
    for (int m = 1; m < 32; m <<= 1) ssum += __shfl_xor(ssum, m, 32);
    float ls = as2[n] + ad2n + selfae2[n];
    ls = ls > 0.f ? ls : 0.2f * ls;
    float ps = __expf(ls);
    ssum += ps;
    acc = fmaf(ps, bf2f(h2b[(unsigned)n * 32u + l32]), acc);
    out[(size_t)n * 32 + l32] = acc / ssum + c2_b[l32];
}

// ---------------------------------------------------------------------------
extern "C" void kernel_launch(void* const* d_in, const int* in_sizes, int n_in,
                              void* d_out, int out_size, void* d_ws, size_t ws_size,
                              hipStream_t stream) {
    const int*   edge_index  = (const int*)  d_in[0];
    const float* edge_attr   = (const float*)d_in[1];
    const float* pol_feat    = (const float*)d_in[2];
    const int*   state_ids   = (const int*)  d_in[3];
    const int*   sector_ids  = (const int*)  d_in[4];
    const int*   industry_ids= (const int*)  d_in[5];
    const float* comp_scalar = (const float*)d_in[6];
    const float* pol_W   = (const float*)d_in[7];
    const float* pol_b   = (const float*)d_in[8];
    const float* state_E = (const float*)d_in[9];
    const float* sector_E= (const float*)d_in[10];
    const float* industry_E=(const float*)d_in[11];
    const float* comp_W  = (const float*)d_in[12];
    const float* comp_b  = (const float*)d_in[13];
    const float* comm_E  = (const float*)d_in[14];
    const float* ln_g    = (const float*)d_in[15];
    const float* ln_b    = (const float*)d_in[16];
    const float* c1_W    = (const float*)d_in[17];
    const float* c1_as   = (const float*)d_in[18];
    const float* c1_ad   = (const float*)d_in[19];
    const float* c1_eW   = (const float*)d_in[20];
    const float* c1_ae   = (const float*)d_in[21];
    const float* c1_b    = (const float*)d_in[22];
    const float* c2_W    = (const float*)d_in[23];
    const float* c2_as   = (const float*)d_in[24];
    const float* c2_ad   = (const float*)d_in[25];
    const float* c2_eW   = (const float*)d_in[26];
    const float* c2_ae   = (const float*)d_in[27];
    const float* c2_b    = (const float*)d_in[28];
    float* out = (float*)d_out;

    char* ws = (char*)d_ws;
    size_t off = 0;
    auto alloc = [&](size_t bytes) { void* p = ws + off; off += (bytes + 255) & ~(size_t)255; return p; };
    int*    bucket_cnt = (int*)   alloc((size_t)NBKT * 16 * 4);
    float4* bucketbuf  = (float4*)alloc((size_t)NBKT * BKTCAP * 16);
    float4* rec2       = (float4*)alloc((size_t)NE * 16);
    int*    deg        = (int*)   alloc(NN * 4);
    int*    erow       = (int*)   alloc(NN * 4);
    float*  selfae2    = (float*) alloc(NN * 4);
    unsigned short* h1b = (unsigned short*)alloc((size_t)NN * 64 * 2);
    float* as1       = (float*)alloc((size_t)NN * 4 * 4);
    float* ad1       = (float*)alloc((size_t)NN * 4 * 4);
    unsigned short* x1b = (unsigned short*)alloc((size_t)NN * 64 * 2);
    unsigned short* h2b = (unsigned short*)alloc((size_t)NN * 32 * 2);
    float* as2       = (float*)alloc(NN * 4);
    float* ad2       = (float*)alloc(NN * 4);
    (void)ws_size; (void)in_sizes; (void)n_in; (void)out_size;

    k_zero<<<1, 1024, 0, stream>>>(bucket_cnt);
    k_featbucket<<<KA_BLOCKS + FEATBLKS, 1024, 0, stream>>>(
        edge_index, edge_attr, c1_eW, c1_ae, c2_eW, c2_ae, bucket_cnt, bucketbuf,
        pol_feat, state_ids, sector_ids, industry_ids, comp_scalar,
        pol_W, pol_b, state_E, sector_E, industry_E, comp_W, comp_b, comm_E,
        ln_g, ln_b, c1_W, c1_as, c1_ad, h1b, as1, ad1);
    k_sortfill<<<NBKT, 1024, 0, stream>>>(
        bucket_cnt, bucketbuf, rec2, deg, erow);
    k_agg1<<<NN / 8, 256, 0, stream>>>(
        erow, deg, rec2, as1, ad1, h1b, c1_b, x1b, selfae2);
    k_mid<<<(NN / 2) / 4, 256, 0, stream>>>(
        x1b, c2_W, c2_as, c2_ad, h2b, as2, ad2);
    k_agg2<<<NN / 8, 256, 0, stream>>>(
        erow, deg, rec2, as2, ad2, selfae2, h2b, c2_b, out);
}

// Round 18
// 158.797 us; speedup vs baseline: 1.0905x; 1.0905x over previous
//
#include <hip/hip_runtime.h>
#include <math.h>

#define NPOL   1000
#define NTICK  98000
#define NCOMM  1000
#define NN     100000
#define NE     1000000

#define BKTSHIFT 9       // 512 nodes per bucket
#define NBKT     196     // ceil(NN/512)
#define BKTCAP   6144    // mean 5120 -> large headroom
#define KA_EPB   4096    // edges per bucket block
#define KA_BLOCKS 245    // ceil(NE/4096)
#define FEATBLKS  391    // ceil(NN*4/1024)

__device__ __forceinline__ unsigned short f2bf(float v) {
    unsigned u = __float_as_uint(v);
    u += 0x7FFFu + ((u >> 16) & 1u);          // round-to-nearest-even
    return (unsigned short)(u >> 16);
}
__device__ __forceinline__ float bf2f(unsigned short s) {
    return __uint_as_float(((unsigned)s) << 16);
}

// ---------------------------------------------------------------------------
__global__ void k_zero(int* __restrict__ bucket_cnt) {
    for (int i = threadIdx.x; i < NBKT * 16; i += 1024) bucket_cnt[i] = 0;
}

// ---------------------------------------------------------------------------
// K_FEATBUCKET: blocks [0,KA_BLOCKS) = edge bucketing (memory/atomic-bound);
// blocks [KA_BLOCKS,..) = node features->LN->h1->as1/ad1 (LDS/VALU-bound).
__global__ void __launch_bounds__(1024) k_featbucket(
    const int* __restrict__ ei, const float* __restrict__ edge_attr,
    const float* __restrict__ c1_eW, const float* __restrict__ c1_ae,
    const float* __restrict__ c2_eW, const float* __restrict__ c2_ae,
    int* __restrict__ bucket_cnt, float4* __restrict__ bucketbuf,
    const float* __restrict__ pol_feat, const int* __restrict__ state_ids,
    const int* __restrict__ sector_ids, const int* __restrict__ industry_ids,
    const float* __restrict__ comp_scalar,
    const float* __restrict__ pol_W, const float* __restrict__ pol_b,
    const float* __restrict__ state_E, const float* __restrict__ sector_E,
    const float* __restrict__ industry_E, const float* __restrict__ comp_W,
    const float* __restrict__ comp_b, const float* __restrict__ comm_E,
    const float* __restrict__ ln_g, const float* __restrict__ ln_b,
    const float* __restrict__ c1_W, const float* __restrict__ c1_as,
    const float* __restrict__ c1_ad,
    unsigned short* __restrict__ h1b, float* __restrict__ as1,
    float* __restrict__ ad1) {
    int t = threadIdx.x;
    if (blockIdx.x < KA_BLOCKS) {
        __shared__ float we1s[20];
        __shared__ float we2s[5];
        __shared__ int hcnt[NBKT];
        __shared__ int hbase[NBKT];
        if (t < 20) {
            int d = t >> 2, h = t & 3;
            float s = 0.f;
            for (int f = 0; f < 16; ++f) s += c1_eW[d * 64 + h * 16 + f] * c1_ae[h * 16 + f];
            we1s[t] = s;
        } else if (t >= 32 && t < 37) {
            int d = t - 32;
            float s = 0.f;
            for (int f = 0; f < 32; ++f) s += c2_eW[d * 32 + f] * c2_ae[f];
            we2s[d] = s;
        }
        if (t < NBKT) hcnt[t] = 0;
        __syncthreads();
        int e0 = blockIdx.x * KA_EPB + t;
        int bk[4], rk[4];
        float4 rec[4];
        #pragma unroll
        for (int k = 0; k < 4; ++k) {
            int e = e0 + k * 1024;
            bk[k] = -1;
            if (e < NE) {
                int s = ei[e];
                int d = ei[NE + e];
                int bkt = d >> BKTSHIFT;
                int dl = d & ((1 << BKTSHIFT) - 1);
                float a[5];
                #pragma unroll
                for (int kk = 0; kk < 5; ++kk) a[kk] = edge_attr[e * 5 + kk];
                float v0 = 0.f, v1 = 0.f, v2 = 0.f, v3 = 0.f, v4 = 0.f;
                #pragma unroll
                for (int kk = 0; kk < 5; ++kk) {
                    v0 += a[kk] * we1s[kk * 4 + 0];
                    v1 += a[kk] * we1s[kk * 4 + 1];
                    v2 += a[kk] * we1s[kk * 4 + 2];
                    v3 += a[kk] * we1s[kk * 4 + 3];
                    v4 += a[kk] * we2s[kk];
                }
                unsigned u01 = (unsigned)f2bf(v0) | ((unsigned)f2bf(v1) << 16);
                unsigned u23 = (unsigned)f2bf(v2) | ((unsigned)f2bf(v3) << 16);
                unsigned pk = (unsigned)s | ((unsigned)dl << 17);
                rec[k] = make_float4(__uint_as_float(pk), __uint_as_float(u01),
                                     __uint_as_float(u23), v4);
                bk[k] = bkt;
                rk[k] = atomicAdd(&hcnt[bkt], 1);
            }
        }
        __syncthreads();
        if (t < NBKT && hcnt[t] > 0) hbase[t] = atomicAdd(&bucket_cnt[t * 16], hcnt[t]);
        __syncthreads();
        #pragma unroll
        for (int k = 0; k < 4; ++k) {
            if (bk[k] >= 0) {
                int pos = hbase[bk[k]] + rk[k];
                if (pos < BKTCAP)
                    bucketbuf[(size_t)bk[k] * BKTCAP + pos] = rec[k];
            }
        }
        return;
    }
    // ---------------- feat part ----------------
    __shared__ float sW1[2048];
    __shared__ float sCompW[544];
    __shared__ float sPolW[224];
    __shared__ float sAs[64], sAd[64];
    __shared__ float sLg[32], sLb[32], sPb[32], sCb[32];
    for (int i = t; i < 2048; i += 1024) sW1[i] = c1_W[i];
    if (t < 544) sCompW[t] = comp_W[t];
    if (t >= 544 && t < 768) sPolW[t - 544] = pol_W[t - 544];
    if (t >= 768 && t < 832) { sAs[t - 768] = c1_as[t - 768]; sAd[t - 768] = c1_ad[t - 768]; }
    if (t >= 832 && t < 864) {
        int i = t - 832;
        sLg[i] = ln_g[i]; sLb[i] = ln_b[i]; sPb[i] = pol_b[i]; sCb[i] = comp_b[i];
    }
    __syncthreads();
    int tid = (blockIdx.x - KA_BLOCKS) * 1024 + t;
    if (tid >= 4 * NN) return;
    int n = tid >> 2, q = tid & 3, jb = q * 8;
    float x[8];
    if (n < NPOL) {
        float f[7];
        #pragma unroll
        for (int i = 0; i < 7; ++i) f[i] = pol_feat[n * 7 + i];
        int sid = state_ids[n];
        #pragma unroll
        for (int jj = 0; jj < 8; ++jj) {
            int j = jb + jj;
            float v = sPb[j];
            #pragma unroll
            for (int i = 0; i < 7; ++i) v += f[i] * sPolW[i * 32 + j];
            v = v > 0.f ? v : 0.f;
            x[jj] = v + state_E[sid * 32 + j];
        }
    } else if (n < NPOL + NTICK) {
        int tt = n - NPOL;
        float f[17];
        int sec = sector_ids[tt], ind = industry_ids[tt];
        #pragma unroll
        for (int i = 0; i < 8; ++i) { f[i] = sector_E[sec * 8 + i]; f[8 + i] = industry_E[ind * 8 + i]; }
        f[16] = comp_scalar[tt];
        #pragma unroll
        for (int jj = 0; jj < 8; ++jj) {
            int j = jb + jj;
            float v = sCb[j];
            #pragma unroll
            for (int i = 0; i < 17; ++i) v += f[i] * sCompW[i * 32 + j];
            x[jj] = v > 0.f ? v : 0.f;
        }
    } else {
        int c = n - (NPOL + NTICK);
        float4 a = *(const float4*)&comm_E[c * 32 + jb];
        float4 b = *(const float4*)&comm_E[c * 32 + jb + 4];
        x[0] = a.x; x[1] = a.y; x[2] = a.z; x[3] = a.w;
        x[4] = b.x; x[5] = b.y; x[6] = b.z; x[7] = b.w;
    }
    float s1 = 0.f;
    #pragma unroll
    for (int jj = 0; jj < 8; ++jj) s1 += x[jj];
    s1 += __shfl_xor(s1, 1); s1 += __shfl_xor(s1, 2);
    float mu = s1 * (1.f / 32.f);
    float s2 = 0.f;
    #pragma unroll
    for (int jj = 0; jj < 8; ++jj) { float dd = x[jj] - mu; s2 += dd * dd; }
    s2 += __shfl_xor(s2, 1); s2 += __shfl_xor(s2, 2);
    float inv = rsqrtf(s2 * (1.f / 32.f) + 1e-5f);
    #pragma unroll
    for (int jj = 0; jj < 8; ++jj) x[jj] = (x[jj] - mu) * inv * sLg[jb + jj] + sLb[jb + jj];
    float4 acc0 = {0,0,0,0}, acc1 = {0,0,0,0}, acc2 = {0,0,0,0}, acc3 = {0,0,0,0};
    int qb = (t & 63) & ~3;
    int jc = q * 16;
    #pragma unroll
    for (int p = 0; p < 4; ++p) {
        #pragma unroll
        for (int jj = 0; jj < 8; ++jj) {
            float xs = __shfl(x[jj], qb + p, 64);
            const float4* wr = (const float4*)&sW1[(p * 8 + jj) * 64 + jc];
            float4 w0 = wr[0], w1 = wr[1], w2 = wr[2], w3 = wr[3];
            acc0.x = fmaf(xs, w0.x, acc0.x); acc0.y = fmaf(xs, w0.y, acc0.y);
            acc0.z = fmaf(xs, w0.z, acc0.z); acc0.w = fmaf(xs, w0.w, acc0.w);
            acc1.x = fmaf(xs, w1.x, acc1.x); acc1.y = fmaf(xs, w1.y, acc1.y);
            acc1.z = fmaf(xs, w1.z, acc1.z); acc1.w = fmaf(xs, w1.w, acc1.w);
            acc2.x = fmaf(xs, w2.x, acc2.x); acc2.y = fmaf(xs, w2.y, acc2.y);
            acc2.z = fmaf(xs, w2.z, acc2.z); acc2.w = fmaf(xs, w2.w, acc2.w);
            acc3.x = fmaf(xs, w3.x, acc3.x); acc3.y = fmaf(xs, w3.y, acc3.y);
            acc3.z = fmaf(xs, w3.z, acc3.z); acc3.w = fmaf(xs, w3.w, acc3.w);
        }
    }
    const float4* asv = (const float4*)sAs;
    const float4* adv = (const float4*)sAd;
    float4 a0 = asv[q * 4], a1 = asv[q * 4 + 1], a2 = asv[q * 4 + 2], a3 = asv[q * 4 + 3];
    float4 b0 = adv[q * 4], b1v = adv[q * 4 + 1], b2v = adv[q * 4 + 2], b3 = adv[q * 4 + 3];
    float av = acc0.x * a0.x + acc0.y * a0.y + acc0.z * a0.z + acc0.w * a0.w
             + acc1.x * a1.x + acc1.y * a1.y + acc1.z * a1.z + acc1.w * a1.w
             + acc2.x * a2.x + acc2.y * a2.y + acc2.z * a2.z + acc2.w * a2.w
             + acc3.x * a3.x + acc3.y * a3.y + acc3.z * a3.z + acc3.w * a3.w;
    float dv = acc0.x * b0.x + acc0.y * b0.y + acc0.z * b0.z + acc0.w * b0.w
             + acc1.x * b1v.x + acc1.y * b1v.y + acc1.z * b1v.z + acc1.w * b1v.w
             + acc2.x * b2v.x + acc2.y * b2v.y + acc2.z * b2v.z + acc2.w * b2v.w
             + acc3.x * b3.x + acc3.y * b3.y + acc3.z * b3.z + acc3.w * b3.w;
    as1[tid] = av;
    ad1[tid] = dv;
    uint4 w1o, w2o;
    w1o.x = (unsigned)f2bf(acc0.x) | ((unsigned)f2bf(acc0.y) << 16);
    w1o.y = (unsigned)f2bf(acc0.z) | ((unsigned)f2bf(acc0.w) << 16);
    w1o.z = (unsigned)f2bf(acc1.x) | ((unsigned)f2bf(acc1.y) << 16);
    w1o.w = (unsigned)f2bf(acc1.z) | ((unsigned)f2bf(acc1.w) << 16);
    w2o.x = (unsigned)f2bf(acc2.x) | ((unsigned)f2bf(acc2.y) << 16);
    w2o.y = (unsigned)f2bf(acc2.z) | ((unsigned)f2bf(acc2.w) << 16);
    w2o.z = (unsigned)f2bf(acc3.x) | ((unsigned)f2bf(acc3.y) << 16);
    w2o.w = (unsigned)f2bf(acc3.z) | ((unsigned)f2bf(acc3.w) << 16);
    unsigned short* hp = h1b + (unsigned)n * 64u + (unsigned)jc;
    *(uint4*)hp = w1o;
    *(uint4*)(hp + 8) = w2o;
}

// ---------------------------------------------------------------------------
// K_SORTFILL: one block per bucket (unchanged).
__global__ void __launch_bounds__(1024) k_sortfill(
    const int* __restrict__ bucket_cnt, const float4* __restrict__ bucketbuf,
    float4* __restrict__ rec2, int* __restrict__ deg, int* __restrict__ erow) {
    __shared__ int pref[256];
    __shared__ int hist[512];
    __shared__ int hoff[512];
    int t = threadIdx.x;
    int b = blockIdx.x;
    if (t < 256) pref[t] = (t < NBKT) ? bucket_cnt[t * 16] : 0;
    if (t < 512) hist[t] = 0;
    __syncthreads();
    for (int off = 1; off < 256; off <<= 1) {
        int v = 0;
        if (t < 256 && t >= off) v = pref[t - off];
        __syncthreads();
        if (t < 256) pref[t] += v;
        __syncthreads();
    }
    int count = bucket_cnt[b * 16];
    if (count > BKTCAP) count = BKTCAP;
    int region = (b == 0) ? 0 : pref[b - 1];
    float4 rv[6];
    int dlv[6], rrv[6];
    #pragma unroll
    for (int k = 0; k < 6; ++k) {
        int i = k * 1024 + t;
        dlv[k] = -1;
        if (i < count) {
            float4 p = bucketbuf[(size_t)b * BKTCAP + i];
            int dl = (int)(__float_as_uint(p.x) >> 17);
            p.x = __uint_as_float(__float_as_uint(p.x) & 0x1FFFFu);
            rv[k] = p;
            dlv[k] = dl;
            rrv[k] = atomicAdd(&hist[dl], 1);
        }
    }
    __syncthreads();
    if (t < 512) hoff[t] = hist[t];
    __syncthreads();
    for (int off = 1; off < 512; off <<= 1) {
        int v = 0;
        if (t < 512 && t >= off) v = hoff[t - off];
        __syncthreads();
        if (t < 512) hoff[t] += v;
        __syncthreads();
    }
    #pragma unroll
    for (int k = 0; k < 6; ++k) {
        if (dlv[k] >= 0) {
            int pos = region + hoff[dlv[k]] - hist[dlv[k]] + rrv[k];
            rec2[pos] = rv[k];
        }
    }
    int n = (b << BKTSHIFT) + t;
    if (t < 512 && n < NN) {
        deg[n] = hist[t];
        erow[n] = region + hoff[t] - hist[t];
    }
}

// ---------------------------------------------------------------------------
// K_AGG1M: GAT layer 1 aggregation (2 nodes/wave) + fused mid GEMV. The R16
// configuration — fused is cheaper at PIPELINE level than split agg1+mid
// (kills x1b round-trip + a kernel-boundary drain), despite the 60us dispatch.
__global__ void __launch_bounds__(256) k_agg1m(
    const int* __restrict__ erow, const int* __restrict__ deg,
    const float4* __restrict__ rec2,
    const float* __restrict__ as1, const float* __restrict__ ad1,
    const unsigned short* __restrict__ h1b, const float* __restrict__ c1_b,
    const float* __restrict__ c2_W, const float* __restrict__ c2_as,
    const float* __restrict__ c2_ad,
    unsigned short* __restrict__ h2b, float* __restrict__ as2,
    float* __restrict__ ad2, float* __restrict__ selfae2) {
    __shared__ float pT[4][2][32][4];
    __shared__ int   srcT[4][2][32];
    int wid = threadIdx.x >> 6;
    int lane = threadIdx.x & 63;
    int half = lane >> 5;
    int j = lane & 31;
    int h = j >> 3;
    int n = blockIdx.x * 8 + wid * 2 + half;
    int base = erow[n];
    int dg   = deg[n];
    const float4* as1v4 = (const float4*)as1;
    const float4* ad1v4 = (const float4*)ad1;
    float4 adv = ad1v4[n];
    float4 asv = as1v4[n];
    unsigned uself = *(const unsigned*)(h1b + (unsigned)n * 64u + 2u * (unsigned)j);

    float ssum = 0.f, acc0 = 0.f, acc1 = 0.f;
    float aes0 = 0.f, aes1 = 0.f, aes2 = 0.f, aes3 = 0.f, ae2sum = 0.f;

    for (int i0 = 0; i0 < dg; i0 += 32) {
        int clen = dg - i0; if (clen > 32) clen = 32;
        int idx = i0 + j;
        if (idx < dg) {
            float4 r = rec2[base + idx];
            int s = __float_as_int(r.x);
            unsigned u01 = __float_as_uint(r.y), u23 = __float_as_uint(r.z);
            float ae0  = bf2f((unsigned short)u01);
            float ae1v = bf2f((unsigned short)(u01 >> 16));
            float ae2v = bf2f((unsigned short)u23);
            float ae3v = bf2f((unsigned short)(u23 >> 16));
            float4 av = as1v4[s];
            float l0 = av.x + adv.x + ae0;  l0 = l0 > 0.f ? l0 : 0.2f * l0;
            float l1 = av.y + adv.y + ae1v; l1 = l1 > 0.f ? l1 : 0.2f * l1;
            float l2 = av.z + adv.z + ae2v; l2 = l2 > 0.f ? l2 : 0.2f * l2;
            float l3 = av.w + adv.w + ae3v; l3 = l3 > 0.f ? l3 : 0.2f * l3;
            float4 q = make_float4(__expf(l0), __expf(l1), __expf(l2), __expf(l3));
            *(float4*)&pT[wid][half][j][0] = q;
            srcT[wid][half][j] = s;
            aes0 += ae0; aes1 += ae1v; aes2 += ae2v; aes3 += ae3v;
            ae2sum += r.w;
        }
        int i = 0;
        for (; i + 4 <= clen; i += 4) {
            int s0 = srcT[wid][half][i],     s1 = srcT[wid][half][i + 1];
            int s2 = srcT[wid][half][i + 2], s3 = srcT[wid][half][i + 3];
            float q0 = pT[wid][half][i][h],     q1 = pT[wid][half][i + 1][h];
            float q2 = pT[wid][half][i + 2][h], q3 = pT[wid][half][i + 3][h];
            unsigned g0 = *(const unsigned*)(h1b + (unsigned)s0 * 64u + 2u * (unsigned)j);
            unsigned g1 = *(const unsigned*)(h1b + (unsigned)s1 * 64u + 2u * (unsigned)j);
            unsigned g2 = *(const unsigned*)(h1b + (unsigned)s2 * 64u + 2u * (unsigned)j);
            unsigned g3 = *(const unsigned*)(h1b + (unsigned)s3 * 64u + 2u * (unsigned)j);
            ssum += (q0 + q1) + (q2 + q3);
            acc0 = fmaf(q0, bf2f((unsigned short)g0),
                   fmaf(q1, bf2f((unsigned short)g1),
                   fmaf(q2, bf2f((unsigned short)g2),
                   fmaf(q3, bf2f((unsigned short)g3), acc0))));
            acc1 = fmaf(q0, bf2f((unsigned short)(g0 >> 16)),
                   fmaf(q1, bf2f((unsigned short)(g1 >> 16)),
                   fmaf(q2, bf2f((unsigned short)(g2 >> 16)),
                   fmaf(q3, bf2f((unsigned short)(g3 >> 16)), acc1))));
        }
        for (; i < clen; ++i) {
            int s0 = srcT[wid][half][i];
            float q0 = pT[wid][half][i][h];
            unsigned g0 = *(const unsigned*)(h1b + (unsigned)s0 * 64u + 2u * (unsigned)j);
            ssum += q0;
            acc0 = fmaf(q0, bf2f((unsigned short)g0), acc0);
            acc1 = fmaf(q0, bf2f((unsigned short)(g0 >> 16)), acc1);
        }
    }
    #pragma unroll
    for (int m = 1; m < 32; m <<= 1) {
        aes0 += __shfl_xor(aes0, m);
        aes1 += __shfl_xor(aes1, m);
        aes2 += __shfl_xor(aes2, m);
        aes3 += __shfl_xor(aes3, m);
        ae2sum += __shfl_xor(ae2sum, m);
    }
    float invd = 1.f / fmaxf((float)dg, 1.f);
    float aesh = (h == 0) ? aes0 : (h == 1) ? aes1 : (h == 2) ? aes2 : aes3;
    float adh  = (h == 0) ? adv.x : (h == 1) ? adv.y : (h == 2) ? adv.z : adv.w;
    float ash  = (h == 0) ? asv.x : (h == 1) ? asv.y : (h == 2) ? asv.z : asv.w;
    float ls = ash + adh + aesh * invd;
    ls = ls > 0.f ? ls : 0.2f * ls;
    float ps = __expf(ls);
    ssum += ps;
    acc0 = fmaf(ps, bf2f((unsigned short)uself), acc0);
    acc1 = fmaf(ps, bf2f((unsigned short)(uself >> 16)), acc1);
    if (lane == 0) selfae2[n] = ae2sum * invd;
    if (lane == 32) selfae2[n] = ae2sum * invd;
    float inv_s = 1.f / ssum;
    float x0 = acc0 * inv_s + c1_b[2 * j];
    float x1 = acc1 * inv_s + c1_b[2 * j + 1];
    x0 = (x0 > 0.f) ? x0 : (__expf(x0) - 1.f);   // ELU
    x1 = (x1 > 0.f) ? x1 : (__expf(x1) - 1.f);
    unsigned w = (unsigned)f2bf(x0) | ((unsigned)f2bf(x1) << 16);
    // ---- fused mid: h2 = x1 @ c2_W (64->32), as2/ad2 ----
    float acc = 0.f;
    #pragma unroll
    for (int tt = 0; tt < 32; ++tt) {
        unsigned xu = (unsigned)__shfl((int)w, half * 32 + tt, 64);
        float xa = bf2f((unsigned short)xu);
        float xb = bf2f((unsigned short)(xu >> 16));
        acc = fmaf(xa, c2_W[(2 * tt) * 32 + j], acc);
        acc = fmaf(xb, c2_W[(2 * tt + 1) * 32 + j], acc);
    }
    float a = acc * c2_as[j], b = acc * c2_ad[j];
    #pragma unroll
    for (int m = 16; m > 0; m >>= 1) {
        a += __shfl_xor(a, m, 64);   // stays within the 32-lane half
        b += __shfl_xor(b, m, 64);
    }
    if (j == 0) { as2[n] = a; ad2[n] = b; }
    h2b[(unsigned)n * 32u + j] = f2bf(acc);
}

// ---------------------------------------------------------------------------
// K7: GAT layer 2, one 32-lane group per dst; self via selfae2 (unchanged).
__global__ void __launch_bounds__(256) k_agg2(
    const int* __restrict__ erow, const int* __restrict__ deg,
    const float4* __restrict__ rec2, const float* __restrict__ as2,
    const float* __restrict__ ad2, const float* __restrict__ selfae2,
    const unsigned short* __restrict__ h2b, const float* __restrict__ c2_b,
    float* __restrict__ out) {
    __shared__ float2 spT[8][32];
    int t = threadIdx.x;
    int half = t >> 5;
    int l32 = t & 31;
    int n = blockIdx.x * 8 + half;
    int base = erow[n];
    int dg = deg[n];
    float ad2n = ad2[n];
    float ssum = 0.f, acc = 0.f;
    for (int i0 = 0; i0 < dg; i0 += 32) {
        int clen = dg - i0; if (clen > 32) clen = 32;
        int idx = i0 + l32;
        float p = 0.f; int s = 0;
        if (idx < dg) {
            float4 r = rec2[base + idx];
            s = __float_as_int(r.x);
            float l = as2[s] + ad2n + r.w;
            l = l > 0.f ? l : 0.2f * l;
            p = __expf(l);
        }
        ssum += p;
        spT[half][l32] = make_float2(__int_as_float(s), p);
        int i = 0;
        for (; i + 4 <= clen; i += 4) {
            float2 e0 = spT[half][i],     e1 = spT[half][i + 1];
            float2 e2 = spT[half][i + 2], e3 = spT[half][i + 3];
            int s0 = __float_as_int(e0.x), s1 = __float_as_int(e1.x);
            int s2 = __float_as_int(e2.x), s3 = __float_as_int(e3.x);
            float g0 = bf2f(h2b[(unsigned)s0 * 32u + l32]);
            float g1 = bf2f(h2b[(unsigned)s1 * 32u + l32]);
            float g2 = bf2f(h2b[(unsigned)s2 * 32u + l32]);
            float g3 = bf2f(h2b[(unsigned)s3 * 32u + l32]);
            acc = fmaf(e0.y, g0, fmaf(e1.y, g1, fmaf(e2.y, g2, fmaf(e3.y, g3, acc))));
        }
        for (; i < clen; ++i) {
            float2 e0 = spT[half][i];
            int s0 = __float_as_int(e0.x);
            acc = fmaf(e0.y, bf2f(h2b[(unsigned)s0 * 32u + l32]), acc);
        }
    }
    #pragma unroll
    for (int m = 1; m < 32; m <<= 1) ssum += __shfl_xor(ssum, m, 32);
    float ls = as2[n] + ad2n + selfae2[n];
    ls = ls > 0.f ? ls : 0.2f * ls;
    float ps = __expf(ls);
    ssum += ps;
    acc = fmaf(ps, bf2f(h2b[(unsigned)n * 32u + l32]), acc);
    out[(size_t)n * 32 + l32] = acc / ssum + c2_b[l32];
}

// ---------------------------------------------------------------------------
extern "C" void kernel_launch(void* const* d_in, const int* in_sizes, int n_in,
                              void* d_out, int out_size, void* d_ws, size_t ws_size,
                              hipStream_t stream) {
    const int*   edge_index  = (const int*)  d_in[0];
    const float* edge_attr   = (const float*)d_in[1];
    const float* pol_feat    = (const float*)d_in[2];
    const int*   state_ids   = (const int*)  d_in[3];
    const int*   sector_ids  = (const int*)  d_in[4];
    const int*   industry_ids= (const int*)  d_in[5];
    const float* comp_scalar = (const float*)d_in[6];
    const float* pol_W   = (const float*)d_in[7];
    const float* pol_b   = (const float*)d_in[8];
    const float* state_E = (const float*)d_in[9];
    const float* sector_E= (const float*)d_in[10];
    const float* industry_E=(const float*)d_in[11];
    const float* comp_W  = (const float*)d_in[12];
    const float* comp_b  = (const float*)d_in[13];
    const float* comm_E  = (const float*)d_in[14];
    const float* ln_g    = (const float*)d_in[15];
    const float* ln_b    = (const float*)d_in[16];
    const float* c1_W    = (const float*)d_in[17];
    const float* c1_as   = (const float*)d_in[18];
    const float* c1_ad   = (const float*)d_in[19];
    const float* c1_eW   = (const float*)d_in[20];
    const float* c1_ae   = (const float*)d_in[21];
    const float* c1_b    = (const float*)d_in[22];
    const float* c2_W    = (const float*)d_in[23];
    const float* c2_as   = (const float*)d_in[24];
    const float* c2_ad   = (const float*)d_in[25];
    const float* c2_eW   = (const float*)d_in[26];
    const float* c2_ae   = (const float*)d_in[27];
    const float* c2_b    = (const float*)d_in[28];
    float* out = (float*)d_out;

    char* ws = (char*)d_ws;
    size_t off = 0;
    auto alloc = [&](size_t bytes) { void* p = ws + off; off += (bytes + 255) & ~(size_t)255; return p; };
    int*    bucket_cnt = (int*)   alloc((size_t)NBKT * 16 * 4);
    float4* bucketbuf  = (float4*)alloc((size_t)NBKT * BKTCAP * 16);
    float4* rec2       = (float4*)alloc((size_t)NE * 16);
    int*    deg        = (int*)   alloc(NN * 4);
    int*    erow       = (int*)   alloc(NN * 4);
    float*  selfae2    = (float*) alloc(NN * 4);
    unsigned short* h1b = (unsigned short*)alloc((size_t)NN * 64 * 2);
    float* as1       = (float*)alloc((size_t)NN * 4 * 4);
    float* ad1       = (float*)alloc((size_t)NN * 4 * 4);
    unsigned short* h2b = (unsigned short*)alloc((size_t)NN * 32 * 2);
    float* as2       = (float*)alloc(NN * 4);
    float* ad2       = (float*)alloc(NN * 4);
    (void)ws_size; (void)in_sizes; (void)n_in; (void)out_size;

    k_zero<<<1, 1024, 0, stream>>>(bucket_cnt);
    k_featbucket<<<KA_BLOCKS + FEATBLKS, 1024, 0, stream>>>(
        edge_index, edge_attr, c1_eW, c1_ae, c2_eW, c2_ae, bucket_cnt, bucketbuf,
        pol_feat, state_ids, sector_ids, industry_ids, comp_scalar,
        pol_W, pol_b, state_E, sector_E, industry_E, comp_W, comp_b, comm_E,
        ln_g, ln_b, c1_W, c1_as, c1_ad, h1b, as1, ad1);
    k_sortfill<<<NBKT, 1024, 0, stream>>>(
        bucket_cnt, bucketbuf, rec2, deg, erow);
    k_agg1m<<<NN / 8, 256, 0, stream>>>(
        erow, deg, rec2, as1, ad1, h1b, c1_b, c2_W, c2_as, c2_ad,
        h2b, as2, ad2, selfae2);
    k_agg2<<<NN / 8, 256, 0, stream>>>(
        erow, deg, rec2, as2, ad2, selfae2, h2b, c2_b, out);
}